// Round 11
// baseline (304.256 us; speedup 1.0000x reference)
//
#include <hip/hip_runtime.h>
#include <hip/hip_bf16.h>
#include <cstdint>
#include <cstddef>

#define B_  32
#define T_  2048
#define D_  1024
#define H_  1024
#define M_  (B_ * T_)   // 65536 rows of t

typedef __attribute__((ext_vector_type(4))) float  f32x4;
typedef __attribute__((ext_vector_type(8))) __bf16 bf16x8;

#define GLOBAL_AS __attribute__((address_space(1)))
#define LDS_AS    __attribute__((address_space(3)))

__device__ __forceinline__ void gload_lds16(const void* g, void* l) {
  __builtin_amdgcn_global_load_lds((const GLOBAL_AS unsigned int*)g,
                                   (LDS_AS unsigned int*)l, 16, 0, 0);
}

__device__ __forceinline__ unsigned int f2bf(float f) {
  unsigned int u = __float_as_uint(f);
  return (u + 0x7fffu + ((u >> 16) & 1u)) >> 16;   // RNE
}
__device__ __forceinline__ unsigned int packbf2(float lo, float hi) {
  return f2bf(lo) | (f2bf(hi) << 16);
}
__device__ __forceinline__ float bfu(unsigned int u) {   // bf16 bits -> f32
  return __uint_as_float(u << 16);
}
__device__ __forceinline__ float fast_tanh(float x) {
  x = fminf(fmaxf(x, -15.f), 15.f);
  float e = __expf(2.f * x);
  return (e - 1.f) / (e + 1.f);
}

// ---------------------------------------------------------------------------
// Prep (small): blocks [0,512): g partials (dc 16 x hs 32), low-VGPR high-TLP;
// blocks [512,1536): wt (DxH f32) -> wtT (HxD bf16) transpose.
// ---------------------------------------------------------------------------
__global__ __launch_bounds__(256) void k_prep_small(const float* __restrict__ wt,
                                                    unsigned short* __restrict__ wtT,
                                                    const float* __restrict__ a,
                                                    const float* __restrict__ b,
                                                    const float* __restrict__ wa,
                                                    const float* __restrict__ wb,
                                                    float* __restrict__ gpa,
                                                    float* __restrict__ gpb) {
  const int bid = blockIdx.x, tid = threadIdx.x;
  if (bid < 512) {
    const int dc = bid >> 5, hs = bid & 31;      // 16 d-chunks x 32 h-slices
    const int d0 = dc * 64;
    const int bb = tid >> 3;                     // 0..31
    const int h4 = hs * 32 + (tid & 7) * 4;      // 4 h per thread
    f32x4 sa = {0.f, 0.f, 0.f, 0.f}, sb = {0.f, 0.f, 0.f, 0.f};
#pragma unroll 8
    for (int di = 0; di < 64; ++di) {
      const int d = d0 + di;
      const float av = a[bb * 1024 + d];
      const float bv = b[bb * 1024 + d];
      const f32x4 wav = *(const f32x4*)(wa + (size_t)d * 1024 + h4);
      const f32x4 wbv = *(const f32x4*)(wb + (size_t)d * 1024 + h4);
      sa += av * wav;
      sb += bv * wbv;
    }
    *(f32x4*)(gpa + (size_t)dc * 32768 + bb * 1024 + h4) = sa;
    *(f32x4*)(gpb + (size_t)dc * 32768 + bb * 1024 + h4) = sb;
  } else {
    __shared__ float tile[32][33];
    const int tile_id = bid - 512;               // 0..1023
    const int tx = tid & 31, ty = tid >> 5;
    const int c0 = (tile_id & 31) * 32, r0 = (tile_id >> 5) * 32;
#pragma unroll
    for (int i = 0; i < 4; ++i)
      tile[ty + i * 8][tx] = wt[(size_t)(r0 + ty + i * 8) * H_ + c0 + tx];
    __syncthreads();
#pragma unroll
    for (int i = 0; i < 4; ++i)
      wtT[(size_t)(c0 + ty + i * 8) * D_ + r0 + tx] = (unsigned short)f2bf(tile[tx][ty + i * 8]);
  }
}

// ---------------------------------------------------------------------------
// g finalize: g[b,h] = tanh(sum_dc gpa) * tanh(sum_dc gpb) * wh[h]
// ---------------------------------------------------------------------------
__global__ __launch_bounds__(256) void k_gfin(const float* __restrict__ gpa,
                                              const float* __restrict__ gpb,
                                              const float* __restrict__ wh,
                                              float* __restrict__ g) {
  const int idx = blockIdx.x * 256 + threadIdx.x;  // 0..32767
  float sa = 0.f, sb = 0.f;
#pragma unroll
  for (int dc = 0; dc < 16; ++dc) {
    sa += gpa[(size_t)dc * 32768 + idx];
    sb += gpb[(size_t)dc * 32768 + idx];
  }
  g[idx] = fast_tanh(sa) * fast_tanh(sb) * wh[idx & 1023];
}

// ---------------------------------------------------------------------------
// t (fp32) -> t_bf16 stream. Nontemporal loads; normal stores (tb re-read).
// ---------------------------------------------------------------------------
__global__ __launch_bounds__(256) void k_tobf16(const float* __restrict__ t,
                                                uint2* __restrict__ ob) {
  const f32x4* t4 = (const f32x4*)t;
  const size_t stride = (size_t)2048 * 256;
  size_t i = (size_t)blockIdx.x * 256 + threadIdx.x;
#pragma unroll 4
  for (; i < (size_t)M_ * 256; i += stride) {
    const f32x4 v = __builtin_nontemporal_load(&t4[i]);
    uint2 o; o.x = packbf2(v.x, v.y); o.y = packbf2(v.z, v.w);
    ob[i] = o;
  }
}

// ---------------------------------------------------------------------------
// 8-phase fused score GEMM v2 (r6 geometry, corrected schedule).
// BM=BN=256, BK=64, 8 waves (2M x 4N), 512 threads, LDS 128KiB
// (A[2buf][2kf][128 row-pairs][64] bf16, B same at +32768 elems).
// Schedule per phase: {ds-subtile load | 1 STAGE} -> s_barrier ->
// lgkmcnt(0) -> setprio(1) -> 16 MFMA -> setprio(0) -> vmcnt(8) -> s_barrier.
// vmcnt(8) = counted (4 STAGEs in flight; min stage->consume distance is
// 5 phases, so end-of-(p+4) vmcnt(8) exactly guarantees landing).
// NO sched_barrier(0) anywhere (r6's 24/iter pinning was the m141 failure).
// Swizzle + staging map byte-identical to r6 (refcheck-passed).
// spart[bn2][row] = sum_{h in 256-col block} tanh((t@wt)[row,h]) * g[b,h]
// ---------------------------------------------------------------------------
__global__ __launch_bounds__(512, 2) void k_score_fast(const unsigned short* __restrict__ tb,
                                                       const unsigned short* __restrict__ wtT,
                                                       const float* __restrict__ g,
                                                       float* __restrict__ spart) {
  __shared__ unsigned short AB[65536];   // 128 KiB
  __shared__ float red[1024];            // [wn][256 rows]
  const int tid = threadIdx.x;
  const int wg  = ((blockIdx.x & 7) << 7) + (blockIdx.x >> 3);  // bijective XCD chunking (1024%8==0)
  const int bm2 = wg >> 2, bn2 = wg & 3;
  const int lane = tid & 63, w = tid >> 6;       // 8 waves
  const int wm = w >> 2, wn = w & 3;             // 2M x 4N
  const int l15 = lane & 15, lk = lane >> 4;
  const int l15h = l15 >> 1;
  const int row0 = bm2 * 256, col0 = bn2 * 256;

  // read-side swizzled chunk offset (elems within a 64-elem row-pair)
  const int xch = ((((l15 & 1) << 2) + lk) ^ l15h) << 3;

  // staging: lane covers (row, kchunk) with chunk pre-swizzle
  const int g_ = lane >> 3, c_ = lane & 7, ci = c_ ^ g_;
  const int rstage = w * 32 + g_ * 2 + (ci >> 2);          // + j*16
  const int kch8 = (ci & 3) * 8;
  const unsigned short* gAb = tb  + (size_t)(row0 + rstage) * 1024 + kch8;
  const unsigned short* gBb = wtT + (size_t)(col0 + rstage) * 1024 + kch8;
  const int ldst0 = w * 1024 + lane * 8;                    // region elem offset, j=0

  f32x4 acc[8][4] = {};
  bf16x8 af[4], bfr[4];

#define STAGE(isA, skf, sbuf, skt)                                              \
  { const unsigned short* s0 = (isA ? gAb : gBb) + (size_t)(skt) * 64 + (skf) * 32; \
    const int rb = (isA ? 0 : 32768) + (sbuf) * 16384 + (skf) * 8192 + ldst0;   \
    gload_lds16(s0, &AB[rb]);                                                   \
    gload_lds16(s0 + 16 * 1024, &AB[rb + 512]); }

#define LDA(mh, kf, buf)                                                        \
  _Pragma("unroll")                                                             \
  for (int mi = 0; mi < 4; ++mi)                                                \
    af[mi] = *(const bf16x8*)(&AB[(buf) * 16384 + (kf) * 8192                   \
              + (wm * 64 + (mh) * 32 + mi * 8 + l15h) * 64 + xch]);

#define LDB(kf, buf)                                                            \
  _Pragma("unroll")                                                             \
  for (int ni = 0; ni < 4; ++ni)                                                \
    bfr[ni] = *(const bf16x8*)(&AB[32768 + (buf) * 16384 + (kf) * 8192          \
              + (wn * 32 + ni * 8 + l15h) * 64 + xch]);

#define MFMAS(mh)                                                               \
  _Pragma("unroll")                                                             \
  for (int mi = 0; mi < 4; ++mi)                                                \
    _Pragma("unroll")                                                           \
    for (int ni = 0; ni < 4; ++ni)                                              \
      acc[(mh) * 4 + mi][ni] =                                                  \
        __builtin_amdgcn_mfma_f32_16x16x32_bf16(af[mi], bfr[ni], acc[(mh) * 4 + mi][ni], 0, 0, 0);

#define PHASE(buf, kf, mh, RELB, SA, SKF, SBUF, SKT)                            \
  { LDA(mh, kf, buf);                                                           \
    if (RELB) { LDB(kf, buf); }                                                 \
    STAGE(SA, SKF, SBUF, SKT);                                                  \
    __builtin_amdgcn_s_barrier();                                               \
    asm volatile("s_waitcnt lgkmcnt(0)" ::: "memory");                          \
    __builtin_amdgcn_s_setprio(1);                                              \
    MFMAS(mh);                                                                  \
    __builtin_amdgcn_s_setprio(0);                                              \
    asm volatile("s_waitcnt vmcnt(8)" ::: "memory");                            \
    __builtin_amdgcn_s_barrier(); }

  // ---- prologue: K-tile 0 (both kf) -> buf0, K-tile 1 kf0 -> buf1
  STAGE(1, 0, 0, 0); STAGE(0, 0, 0, 0);
  STAGE(1, 1, 0, 0); STAGE(0, 1, 0, 0);
  STAGE(1, 0, 1, 1); STAGE(0, 0, 1, 1);
  asm volatile("s_waitcnt vmcnt(8)" ::: "memory");   // first 4 loads (b0.kf0) landed
  __builtin_amdgcn_s_barrier();

  // ---- main loop: 8 iterations x 2 K-tiles (16 total)
  for (int i = 0; i < 8; ++i) {
    const int kB1 = (2 * i + 1) & 15;   // buf1's current tile
    const int kA  = (2 * i + 2) & 15;   // next buf0 tile
    const int kB3 = (2 * i + 3) & 15;   // next buf1 tile
    PHASE(0, 0, 0, 1, 1, 1, 1, kB1)  // p1: b0.kf0.mh0 | stage A.kf1.b1
    PHASE(0, 0, 1, 0, 0, 1, 1, kB1)  // p2: b0.kf0.mh1 | stage B.kf1.b1
    PHASE(0, 1, 0, 1, 1, 0, 0, kA )  // p3: b0.kf1.mh0 | stage A.kf0.b0
    PHASE(0, 1, 1, 0, 0, 0, 0, kA )  // p4: b0.kf1.mh1 | stage B.kf0.b0
    PHASE(1, 0, 0, 1, 1, 1, 0, kA )  // p5: b1.kf0.mh0 | stage A.kf1.b0
    PHASE(1, 0, 1, 0, 0, 1, 0, kA )  // p6: b1.kf0.mh1 | stage B.kf1.b0
    PHASE(1, 1, 0, 1, 1, 0, 1, kB3)  // p7: b1.kf1.mh0 | stage A.kf0.b1
    PHASE(1, 1, 1, 0, 0, 0, 1, kB3)  // p8: b1.kf1.mh1 | stage B.kf0.b1
  }

  // ---- epilogue: tanh, * g[b,h], reduce over this block's 256 h-columns
  const int b = row0 >> 11;
  float gv[4];
#pragma unroll
  for (int ni = 0; ni < 4; ++ni)
    gv[ni] = g[b * H_ + col0 + wn * 64 + ni * 16 + l15];
#pragma unroll
  for (int mh = 0; mh < 2; ++mh) {
#pragma unroll
    for (int mi = 0; mi < 4; ++mi) {
#pragma unroll
      for (int r = 0; r < 4; ++r) {
        float s = 0.f;
#pragma unroll
        for (int ni = 0; ni < 4; ++ni)
          s += fast_tanh(acc[mh * 4 + mi][ni][r]) * gv[ni];
        s += __shfl_xor(s, 1); s += __shfl_xor(s, 2);
        s += __shfl_xor(s, 4); s += __shfl_xor(s, 8);
        if (l15 == 0)
          red[wn * 256 + wm * 128 + mh * 64 + mi * 16 + lk * 4 + r] = s;
      }
    }
  }
  __syncthreads();
  if (tid < 256)
    spart[(size_t)bn2 * M_ + row0 + tid] =
      (red[tid] + red[256 + tid]) + (red[512 + tid] + red[768 + tid]);
#undef STAGE
#undef LDA
#undef LDB
#undef MFMAS
#undef PHASE
}

// ---------------------------------------------------------------------------
// Fallback fused score GEMM (reg-staged fp32->bf16), used if ws too small.
// ---------------------------------------------------------------------------
__global__ __launch_bounds__(256) void k_score_rs(const float* __restrict__ t,
                                                  const unsigned short* __restrict__ wtT,
                                                  const float* __restrict__ g,
                                                  float* __restrict__ spart) {
  __shared__ unsigned short As[128 * 72];
  __shared__ unsigned short Bs[128 * 72];
  __shared__ float red[256];
  const int tid = threadIdx.x;
  const int bn = blockIdx.x, bm = blockIdx.y;
  const int lane = tid & 63, w = tid >> 6;
  const int wm = w >> 1, wn = w & 1;
  const int l15 = lane & 15, lk = lane >> 4;
  const int row0 = bm * 128, col0 = bn * 128;
  const int ar = tid >> 2, ac = (tid & 3) * 16;
  const int brn = tid >> 1, bco = (tid & 1) * 32;

  f32x4 acc[4][4] = {};

  for (int kt = 0; kt < 16; ++kt) {
    const int k0 = kt * 64;
    __syncthreads();
#pragma unroll
    for (int half = 0; half < 2; ++half) {
      const int r = ar + half * 64;
      const float4* src = (const float4*)(t + (size_t)(row0 + r) * 1024 + k0 + ac);
      float4 v0 = src[0], v1 = src[1], v2 = src[2], v3 = src[3];
      uint4 p0, p1;
      p0.x = packbf2(v0.x, v0.y); p0.y = packbf2(v0.z, v0.w);
      p0.z = packbf2(v1.x, v1.y); p0.w = packbf2(v1.z, v1.w);
      p1.x = packbf2(v2.x, v2.y); p1.y = packbf2(v2.z, v2.w);
      p1.z = packbf2(v3.x, v3.y); p1.w = packbf2(v3.z, v3.w);
      uint4* dst = (uint4*)(&As[r * 72 + ac]);
      dst[0] = p0; dst[1] = p1;
    }
    {
      const uint4* src = (const uint4*)(wtT + (size_t)(col0 + brn) * 1024 + k0 + bco);
      uint4 x0 = src[0], x1 = src[1], x2 = src[2], x3 = src[3];
      uint4* dst = (uint4*)(&Bs[brn * 72 + bco]);
      dst[0] = x0; dst[1] = x1; dst[2] = x2; dst[3] = x3;
    }
    __syncthreads();
#pragma unroll
    for (int kf = 0; kf < 2; ++kf) {
      bf16x8 af[4], bfr[4];
#pragma unroll
      for (int mi = 0; mi < 4; ++mi)
        af[mi] = *(const bf16x8*)(&As[(wm * 64 + mi * 16 + l15) * 72 + kf * 32 + lk * 8]);
#pragma unroll
      for (int ni = 0; ni < 4; ++ni)
        bfr[ni] = *(const bf16x8*)(&Bs[(wn * 64 + ni * 16 + l15) * 72 + kf * 32 + lk * 8]);
#pragma unroll
      for (int mi = 0; mi < 4; ++mi)
#pragma unroll
        for (int ni = 0; ni < 4; ++ni)
          acc[mi][ni] = __builtin_amdgcn_mfma_f32_16x16x32_bf16(af[mi], bfr[ni], acc[mi][ni], 0, 0, 0);
    }
  }

  const int b = row0 >> 11;
  float gv[4];
#pragma unroll
  for (int ni = 0; ni < 4; ++ni)
    gv[ni] = g[b * H_ + col0 + wn * 64 + ni * 16 + l15];
#pragma unroll
  for (int mi = 0; mi < 4; ++mi) {
#pragma unroll
    for (int r = 0; r < 4; ++r) {
      float s = 0.f;
#pragma unroll
      for (int ni = 0; ni < 4; ++ni)
        s += fast_tanh(acc[mi][ni][r]) * gv[ni];
      s += __shfl_xor(s, 1); s += __shfl_xor(s, 2);
      s += __shfl_xor(s, 4); s += __shfl_xor(s, 8);
      if (l15 == 0)
        red[wn * 128 + wm * 64 + mi * 16 + lk * 4 + r] = s;
    }
  }
  __syncthreads();
  if (tid < 128)
    spart[(size_t)bn * M_ + row0 + tid] = red[tid] + red[128 + tid];
}

// ---------------------------------------------------------------------------
// Softmax + mask + renormalize, with inline mask-layout detection.
// ---------------------------------------------------------------------------
__global__ __launch_bounds__(256) void k_softmax(const float* __restrict__ spart,
                                                 const void* __restrict__ mask,
                                                 float* __restrict__ att,
                                                 int nplanes) {
  __shared__ float redmax[4], redsum[4];
  __shared__ int shflag[4];
  const int b = blockIdx.x, tid = threadIdx.x;

  {
    const unsigned int* mw = (const unsigned int*)mask;
    int any = 0;
    for (int i = tid; i < 16384; i += 256)
      if (mw[i] > 1u) any = 1;
    const int wa = __any(any) ? 1 : 0;
    if ((tid & 63) == 0) shflag[tid >> 6] = wa;
  }

  float s[8];
#pragma unroll
  for (int j = 0; j < 8; ++j) {
    const int idx = tid + j * 256;
    float v = 0.f;
    for (int nb = 0; nb < nplanes; ++nb) v += spart[(size_t)nb * M_ + b * T_ + idx];
    s[j] = v;
  }
  float mx = s[0];
#pragma unroll
  for (int j = 1; j < 8; ++j) mx = fmaxf(mx, s[j]);
  for (int o = 1; o < 64; o <<= 1) mx = fmaxf(mx, __shfl_xor(mx, o));
  if ((tid & 63) == 0) redmax[tid >> 6] = mx;
  __syncthreads();
  mx = fmaxf(fmaxf(redmax[0], redmax[1]), fmaxf(redmax[2], redmax[3]));
  const int byte_mode = shflag[0] | shflag[1] | shflag[2] | shflag[3];

  float e[8];
  float sum = 0.f;
#pragma unroll
  for (int j = 0; j < 8; ++j) {
    const int idx = tid + j * 256;
    float v = __expf(s[j] - mx);
    const int mv = byte_mode ? (int)((const unsigned char*)mask)[b * T_ + idx]
                             : ((const int*)mask)[b * T_ + idx];
    v = (mv != 0) ? v : 0.f;
    e[j] = v;
    sum += v;
  }
  for (int o = 1; o < 64; o <<= 1) sum += __shfl_xor(sum, o);
  if ((tid & 63) == 0) redsum[tid >> 6] = sum;
  __syncthreads();
  sum = redsum[0] + redsum[1] + redsum[2] + redsum[3];
  const float inv = 1.f / sum;
#pragma unroll
  for (int j = 0; j < 8; ++j)
    att[b * T_ + tid + j * 256] = e[j] * inv;
}

// ---------------------------------------------------------------------------
// Pooling on bf16 t: pp[tc][b][d] = sum att * tb
// ---------------------------------------------------------------------------
__global__ __launch_bounds__(256) void k_pool_bf(const unsigned short* __restrict__ tb,
                                                 const float* __restrict__ att,
                                                 float* __restrict__ pp) {
  const int b = blockIdx.x, tc = blockIdx.y, tid = threadIdx.x;
  const uint2* tp = (const uint2*)tb;
  float4 acc = make_float4(0.f, 0.f, 0.f, 0.f);
  const int tbase = tc * 128;
  for (int i = 0; i < 128; ++i) {
    const int ti = tbase + i;
    const float wv = att[b * T_ + ti];
    const uint2 v = tp[(size_t)(b * T_ + ti) * 256 + tid];
    acc.x += wv * bfu(v.x & 0xffffu);
    acc.y += wv * bfu(v.x >> 16);
    acc.z += wv * bfu(v.y & 0xffffu);
    acc.w += wv * bfu(v.y >> 16);
  }
  ((float4*)pp)[(size_t)tc * 8192 + b * 256 + tid] = acc;
}

// Fallback pooling on fp32 t.
__global__ __launch_bounds__(256) void k_pool_f32(const float* __restrict__ t,
                                                  const float* __restrict__ att,
                                                  float* __restrict__ pp) {
  const int b = blockIdx.x, tc = blockIdx.y, tid = threadIdx.x;
  const float4* tp = (const float4*)t;
  float4 acc = make_float4(0.f, 0.f, 0.f, 0.f);
  const int tbase = tc * 128;
  for (int i = 0; i < 128; ++i) {
    const int ti = tbase + i;
    const float w = att[b * T_ + ti];
    const float4 v = tp[(size_t)(b * T_ + ti) * 256 + tid];
    acc.x += w * v.x; acc.y += w * v.y; acc.z += w * v.z; acc.w += w * v.w;
  }
  ((float4*)pp)[(size_t)tc * 8192 + b * 256 + tid] = acc;
}

__global__ __launch_bounds__(256) void k_pool_reduce(const float* __restrict__ pp,
                                                     float* __restrict__ out) {
  const int idx = blockIdx.x * 256 + threadIdx.x;  // 0 .. 32767
  float s = 0.f;
#pragma unroll
  for (int tc = 0; tc < 16; ++tc) s += pp[tc * 32768 + idx];
  out[idx] = s;
}

// ---------------------------------------------------------------------------
extern "C" void kernel_launch(void* const* d_in, const int* in_sizes, int n_in,
                              void* d_out, int out_size, void* d_ws, size_t ws_size,
                              hipStream_t stream) {
  const float* t    = (const float*)d_in[0];
  const float* a    = (const float*)d_in[1];
  const float* b    = (const float*)d_in[2];
  const void*  mask = d_in[3];
  const float* wt   = (const float*)d_in[4];
  const float* wa   = (const float*)d_in[5];
  const float* wb   = (const float*)d_in[6];
  const float* wh   = (const float*)d_in[7];
  float* out = (float*)d_out;

  float* ws = (float*)d_ws;
  const size_t NEED_FAST = (size_t)(33554432 + 32768 + 65536 + 524288 + 524288 + 524288) * 4;
  const bool fast = ws_size >= NEED_FAST;

  if (fast) {
    unsigned short* tb = (unsigned short*)ws;          // 128 MB
    float* g     = ws + 33554432;
    float* att   = g + 32768;
    float* spart = att + 65536;                        // 524288 floats (2 MB)
    float* pp    = spart + 524288;                     // 524288 floats (2 MB)
    unsigned short* wtT = (unsigned short*)(pp + 524288);
    float* gpa = spart;                                // overlay, freed by k_gfin
    float* gpb = pp;

    k_prep_small<<<1536, 256, 0, stream>>>(wt, wtT, a, b, wa, wb, gpa, gpb);
    k_gfin<<<128, 256, 0, stream>>>(gpa, gpb, wh, g);
    k_tobf16<<<2048, 256, 0, stream>>>(t, (uint2*)tb);
    k_score_fast<<<1024, 512, 0, stream>>>(tb, wtT, g, spart);
    k_softmax<<<32, 256, 0, stream>>>(spart, mask, att, 4);
    k_pool_bf<<<dim3(32, 16), 256, 0, stream>>>(tb, att, pp);
    k_pool_reduce<<<128, 256, 0, stream>>>(pp, out);
  } else {
    float* g     = ws;
    float* att   = ws + 32768;
    float* spart = ws + 98304;                         // 524288 floats
    float* pp    = ws + 622592;                        // 524288 floats
    unsigned short* wtT = (unsigned short*)(ws + 1146880);
    float* gpa = spart;
    float* gpb = pp;

    k_prep_small<<<1536, 256, 0, stream>>>(wt, wtT, a, b, wa, wb, gpa, gpb);
    k_gfin<<<128, 256, 0, stream>>>(gpa, gpb, wh, g);
    k_score_rs<<<dim3(8, 512), 256, 0, stream>>>(t, wtT, g, spart);
    k_softmax<<<32, 256, 0, stream>>>(spart, mask, att, 8);
    k_pool_f32<<<dim3(32, 16), 256, 0, stream>>>(t, att, pp);
    k_pool_reduce<<<128, 256, 0, stream>>>(pp, out);
  }
}

// Round 12
// 273.828 us; speedup vs baseline: 1.1111x; 1.1111x over previous
//
#include <hip/hip_runtime.h>
#include <hip/hip_bf16.h>
#include <cstdint>
#include <cstddef>

#define B_  32
#define T_  2048
#define D_  1024
#define H_  1024
#define M_  (B_ * T_)   // 65536 rows of t

typedef __attribute__((ext_vector_type(4))) float  f32x4;
typedef __attribute__((ext_vector_type(8))) __bf16 bf16x8;

#define GLOBAL_AS __attribute__((address_space(1)))
#define LDS_AS    __attribute__((address_space(3)))

__device__ __forceinline__ void gload_lds16(const void* g, void* l) {
  __builtin_amdgcn_global_load_lds((const GLOBAL_AS unsigned int*)g,
                                   (LDS_AS unsigned int*)l, 16, 0, 0);
}

__device__ __forceinline__ unsigned int f2bf(float f) {
  unsigned int u = __float_as_uint(f);
  return (u + 0x7fffu + ((u >> 16) & 1u)) >> 16;   // RNE
}
__device__ __forceinline__ unsigned int packbf2(float lo, float hi) {
  return f2bf(lo) | (f2bf(hi) << 16);
}
__device__ __forceinline__ float bfu(unsigned int u) {   // bf16 bits -> f32
  return __uint_as_float(u << 16);
}
__device__ __forceinline__ float fast_tanh(float x) {
  x = fminf(fmaxf(x, -15.f), 15.f);
  float e = __expf(2.f * x);
  return (e - 1.f) / (e + 1.f);
}

// ---------------------------------------------------------------------------
// Fused prep+stream (one dispatch; all three parts are mutually independent,
// all must precede k_score). Every branch is register-light (r8 lesson:
// coupled VGPR allocation must not starve any branch; g uses 8-VGPR accs).
//   blocks [0,512):      g partials (dc 16 x hs 32), low-VGPR high-TLP
//   blocks [512,1536):   wt (DxH f32) -> wtT (HxD bf16) transpose
//   blocks [1536,3584):  t (f32) -> tb (bf16) stream (HBM-bound long pole)
// ---------------------------------------------------------------------------
__global__ __launch_bounds__(256) void k_prep_stream(const float* __restrict__ t,
                                                     uint2* __restrict__ tb2,
                                                     const float* __restrict__ wt,
                                                     unsigned short* __restrict__ wtT,
                                                     const float* __restrict__ a,
                                                     const float* __restrict__ b,
                                                     const float* __restrict__ wa,
                                                     const float* __restrict__ wb,
                                                     float* __restrict__ gpa,
                                                     float* __restrict__ gpb) {
  const int bid = blockIdx.x, tid = threadIdx.x;
  if (bid < 512) {
    const int dc = bid >> 5, hs = bid & 31;      // 16 d-chunks x 32 h-slices
    const int d0 = dc * 64;
    const int bb = tid >> 3;                     // 0..31
    const int h4 = hs * 32 + (tid & 7) * 4;      // 4 h per thread
    f32x4 sa = {0.f, 0.f, 0.f, 0.f}, sb = {0.f, 0.f, 0.f, 0.f};
#pragma unroll 8
    for (int di = 0; di < 64; ++di) {
      const int d = d0 + di;
      const float av = a[bb * 1024 + d];
      const float bv = b[bb * 1024 + d];
      const f32x4 wav = *(const f32x4*)(wa + (size_t)d * 1024 + h4);
      const f32x4 wbv = *(const f32x4*)(wb + (size_t)d * 1024 + h4);
      sa += av * wav;
      sb += bv * wbv;
    }
    *(f32x4*)(gpa + (size_t)dc * 32768 + bb * 1024 + h4) = sa;
    *(f32x4*)(gpb + (size_t)dc * 32768 + bb * 1024 + h4) = sb;
  } else if (bid < 1536) {
    __shared__ float tile[32][33];
    const int tile_id = bid - 512;               // 0..1023
    const int tx = tid & 31, ty = tid >> 5;
    const int c0 = (tile_id & 31) * 32, r0 = (tile_id >> 5) * 32;
#pragma unroll
    for (int i = 0; i < 4; ++i)
      tile[ty + i * 8][tx] = wt[(size_t)(r0 + ty + i * 8) * H_ + c0 + tx];
    __syncthreads();
#pragma unroll
    for (int i = 0; i < 4; ++i)
      wtT[(size_t)(c0 + ty + i * 8) * D_ + r0 + tx] = (unsigned short)f2bf(tile[tx][ty + i * 8]);
  } else {
    const f32x4* t4 = (const f32x4*)t;
    const int cb = bid - 1536;                   // 0..2047
    const size_t stride = (size_t)2048 * 256;
    size_t i = (size_t)cb * 256 + tid;
#pragma unroll 4
    for (; i < (size_t)M_ * 256; i += stride) {
      const f32x4 v = __builtin_nontemporal_load(&t4[i]);
      uint2 o; o.x = packbf2(v.x, v.y); o.y = packbf2(v.z, v.w);
      tb2[i] = o;
    }
  }
}

// ---------------------------------------------------------------------------
// g finalize: g[b,h] = tanh(sum_dc gpa) * tanh(sum_dc gpb) * wh[h]
// ---------------------------------------------------------------------------
__global__ __launch_bounds__(256) void k_gfin(const float* __restrict__ gpa,
                                              const float* __restrict__ gpb,
                                              const float* __restrict__ wh,
                                              float* __restrict__ g) {
  const int idx = blockIdx.x * 256 + threadIdx.x;  // 0..32767
  float sa = 0.f, sb = 0.f;
#pragma unroll
  for (int dc = 0; dc < 16; ++dc) {
    sa += gpa[(size_t)dc * 32768 + idx];
    sb += gpb[(size_t)dc * 32768 + idx];
  }
  g[idx] = fast_tanh(sa) * fast_tanh(sb) * wh[idx & 1023];
}

// ---------------------------------------------------------------------------
// FAST fused score GEMM (r5/r10-proven, 155us @ 886 TF): 256x128 tile, BK=64,
// 8 waves (4M x 2N), 512 threads, gload_lds + both-sides XOR swizzle,
// XCD-bijective grid swizzle. MfmaUtil 40%, conflicts 0.
// Two 8-phase ports (r6: 207us, r11: 198us) both regressed — at K=1024 the
// deep pipeline's prologue/epilogue per 1-block/CU round never amortizes.
// This 2-barrier structure + cross-block wave overlap is the proven optimum.
// ---------------------------------------------------------------------------
__global__ __launch_bounds__(512) void k_score_fast(const unsigned short* __restrict__ tb,
                                                    const unsigned short* __restrict__ wtT,
                                                    const float* __restrict__ g,
                                                    float* __restrict__ spart) {
  __shared__ unsigned short As[256 * 64];   // 32 KB  [row][k] linear+swz
  __shared__ unsigned short Bs[128 * 64];   // 16 KB  [n][k]  linear+swz
  __shared__ float red[512];                // [wn][256 rows]
  const int tid = threadIdx.x;
  const int wg  = (blockIdx.x & 7) * 256 + (blockIdx.x >> 3);  // bijective
  const int bm2 = wg >> 3, bn = wg & 7;
  const int lane = tid & 63, w = tid >> 6;       // 8 waves
  const int wm = w >> 1, wn = w & 1;             // 4 x 2
  const int l15 = lane & 15, lk = lane >> 4;
  const int axk = l15 & 7;                       // read-side XOR key
  const int row0 = bm2 * 256, col0 = bn * 128;

  const int srow = lane >> 3;                    // 8 rows per 1KB issue
  const int scol = (((lane & 7) ^ srow) * 8);    // swizzled 16B chunk
  const unsigned short* gA = tb  + (size_t)(row0 + w * 32 + srow) * 1024 + scol;
  const unsigned short* gB = wtT + (size_t)(col0 + w * 16 + srow) * 1024 + scol;
  unsigned short* lA = &As[(w * 32) * 64];
  unsigned short* lB = &Bs[(w * 16) * 64];

  f32x4 acc[4][4] = {};

  for (int kt = 0; kt < 16; ++kt) {
    const int k0 = kt * 64;
    __syncthreads();
#pragma unroll
    for (int i = 0; i < 4; ++i)
      gload_lds16(gA + (size_t)i * 8192 + k0, lA + i * 512);
#pragma unroll
    for (int j = 0; j < 2; ++j)
      gload_lds16(gB + (size_t)j * 8192 + k0, lB + j * 512);
    __syncthreads();
#pragma unroll
    for (int kf = 0; kf < 2; ++kf) {
      bf16x8 af[4], bfr[4];
#pragma unroll
      for (int mi = 0; mi < 4; ++mi)
        af[mi] = *(const bf16x8*)(&As[(wm * 64 + mi * 16 + l15) * 64
                                      + (((kf * 4 + lk) ^ axk) << 3)]);
#pragma unroll
      for (int ni = 0; ni < 4; ++ni)
        bfr[ni] = *(const bf16x8*)(&Bs[(wn * 64 + ni * 16 + l15) * 64
                                       + (((kf * 4 + lk) ^ axk) << 3)]);
#pragma unroll
      for (int mi = 0; mi < 4; ++mi)
#pragma unroll
        for (int ni = 0; ni < 4; ++ni)
          acc[mi][ni] = __builtin_amdgcn_mfma_f32_16x16x32_bf16(af[mi], bfr[ni], acc[mi][ni], 0, 0, 0);
    }
  }

  const int b = row0 >> 11;
  float gv[4];
#pragma unroll
  for (int ni = 0; ni < 4; ++ni)
    gv[ni] = g[b * H_ + col0 + wn * 64 + ni * 16 + l15];
#pragma unroll
  for (int mi = 0; mi < 4; ++mi) {
#pragma unroll
    for (int r = 0; r < 4; ++r) {
      float s = 0.f;
#pragma unroll
      for (int ni = 0; ni < 4; ++ni)
        s += fast_tanh(acc[mi][ni][r]) * gv[ni];
      s += __shfl_xor(s, 1); s += __shfl_xor(s, 2);
      s += __shfl_xor(s, 4); s += __shfl_xor(s, 8);
      if (l15 == 0)
        red[wn * 256 + wm * 64 + mi * 16 + lk * 4 + r] = s;
    }
  }
  __syncthreads();
  if (tid < 256)
    spart[(size_t)bn * M_ + row0 + tid] = red[tid] + red[256 + tid];
}

// ---------------------------------------------------------------------------
// Fallback fused score GEMM (reg-staged fp32->bf16), used if ws too small.
// ---------------------------------------------------------------------------
__global__ __launch_bounds__(256) void k_score_rs(const float* __restrict__ t,
                                                  const unsigned short* __restrict__ wtT,
                                                  const float* __restrict__ g,
                                                  float* __restrict__ spart) {
  __shared__ unsigned short As[128 * 72];
  __shared__ unsigned short Bs[128 * 72];
  __shared__ float red[256];
  const int tid = threadIdx.x;
  const int bn = blockIdx.x, bm = blockIdx.y;
  const int lane = tid & 63, w = tid >> 6;
  const int wm = w >> 1, wn = w & 1;
  const int l15 = lane & 15, lk = lane >> 4;
  const int row0 = bm * 128, col0 = bn * 128;
  const int ar = tid >> 2, ac = (tid & 3) * 16;
  const int brn = tid >> 1, bco = (tid & 1) * 32;

  f32x4 acc[4][4] = {};

  for (int kt = 0; kt < 16; ++kt) {
    const int k0 = kt * 64;
    __syncthreads();
#pragma unroll
    for (int half = 0; half < 2; ++half) {
      const int r = ar + half * 64;
      const float4* src = (const float4*)(t + (size_t)(row0 + r) * 1024 + k0 + ac);
      float4 v0 = src[0], v1 = src[1], v2 = src[2], v3 = src[3];
      uint4 p0, p1;
      p0.x = packbf2(v0.x, v0.y); p0.y = packbf2(v0.z, v0.w);
      p0.z = packbf2(v1.x, v1.y); p0.w = packbf2(v1.z, v1.w);
      p1.x = packbf2(v2.x, v2.y); p1.y = packbf2(v2.z, v2.w);
      p1.z = packbf2(v3.x, v3.y); p1.w = packbf2(v3.z, v3.w);
      uint4* dst = (uint4*)(&As[r * 72 + ac]);
      dst[0] = p0; dst[1] = p1;
    }
    {
      const uint4* src = (const uint4*)(wtT + (size_t)(col0 + brn) * 1024 + k0 + bco);
      uint4 x0 = src[0], x1 = src[1], x2 = src[2], x3 = src[3];
      uint4* dst = (uint4*)(&Bs[brn * 72 + bco]);
      dst[0] = x0; dst[1] = x1; dst[2] = x2; dst[3] = x3;
    }
    __syncthreads();
#pragma unroll
    for (int kf = 0; kf < 2; ++kf) {
      bf16x8 af[4], bfr[4];
#pragma unroll
      for (int mi = 0; mi < 4; ++mi)
        af[mi] = *(const bf16x8*)(&As[(wm * 64 + mi * 16 + l15) * 72 + kf * 32 + lk * 8]);
#pragma unroll
      for (int ni = 0; ni < 4; ++ni)
        bfr[ni] = *(const bf16x8*)(&Bs[(wn * 64 + ni * 16 + l15) * 72 + kf * 32 + lk * 8]);
#pragma unroll
      for (int mi = 0; mi < 4; ++mi)
#pragma unroll
        for (int ni = 0; ni < 4; ++ni)
          acc[mi][ni] = __builtin_amdgcn_mfma_f32_16x16x32_bf16(af[mi], bfr[ni], acc[mi][ni], 0, 0, 0);
    }
  }

  const int b = row0 >> 11;
  float gv[4];
#pragma unroll
  for (int ni = 0; ni < 4; ++ni)
    gv[ni] = g[b * H_ + col0 + wn * 64 + ni * 16 + l15];
#pragma unroll
  for (int mi = 0; mi < 4; ++mi) {
#pragma unroll
    for (int r = 0; r < 4; ++r) {
      float s = 0.f;
#pragma unroll
      for (int ni = 0; ni < 4; ++ni)
        s += fast_tanh(acc[mi][ni][r]) * gv[ni];
      s += __shfl_xor(s, 1); s += __shfl_xor(s, 2);
      s += __shfl_xor(s, 4); s += __shfl_xor(s, 8);
      if (l15 == 0)
        red[wn * 128 + wm * 64 + mi * 16 + lk * 4 + r] = s;
    }
  }
  __syncthreads();
  if (tid < 128)
    spart[(size_t)bn * M_ + row0 + tid] = red[tid] + red[128 + tid];
}

// ---------------------------------------------------------------------------
// Softmax + mask + renormalize, with inline mask-layout detection.
// ---------------------------------------------------------------------------
__global__ __launch_bounds__(256) void k_softmax(const float* __restrict__ spart,
                                                 const void* __restrict__ mask,
                                                 float* __restrict__ att,
                                                 int nplanes) {
  __shared__ float redmax[4], redsum[4];
  __shared__ int shflag[4];
  const int b = blockIdx.x, tid = threadIdx.x;

  {
    const unsigned int* mw = (const unsigned int*)mask;
    int any = 0;
    for (int i = tid; i < 16384; i += 256)
      if (mw[i] > 1u) any = 1;
    const int wa = __any(any) ? 1 : 0;
    if ((tid & 63) == 0) shflag[tid >> 6] = wa;
  }

  float s[8];
#pragma unroll
  for (int j = 0; j < 8; ++j) {
    const int idx = tid + j * 256;
    float v = 0.f;
    for (int nb = 0; nb < nplanes; ++nb) v += spart[(size_t)nb * M_ + b * T_ + idx];
    s[j] = v;
  }
  float mx = s[0];
#pragma unroll
  for (int j = 1; j < 8; ++j) mx = fmaxf(mx, s[j]);
  for (int o = 1; o < 64; o <<= 1) mx = fmaxf(mx, __shfl_xor(mx, o));
  if ((tid & 63) == 0) redmax[tid >> 6] = mx;
  __syncthreads();
  mx = fmaxf(fmaxf(redmax[0], redmax[1]), fmaxf(redmax[2], redmax[3]));
  const int byte_mode = shflag[0] | shflag[1] | shflag[2] | shflag[3];

  float e[8];
  float sum = 0.f;
#pragma unroll
  for (int j = 0; j < 8; ++j) {
    const int idx = tid + j * 256;
    float v = __expf(s[j] - mx);
    const int mv = byte_mode ? (int)((const unsigned char*)mask)[b * T_ + idx]
                             : ((const int*)mask)[b * T_ + idx];
    v = (mv != 0) ? v : 0.f;
    e[j] = v;
    sum += v;
  }
  for (int o = 1; o < 64; o <<= 1) sum += __shfl_xor(sum, o);
  if ((tid & 63) == 0) redsum[tid >> 6] = sum;
  __syncthreads();
  sum = redsum[0] + redsum[1] + redsum[2] + redsum[3];
  const float inv = 1.f / sum;
#pragma unroll
  for (int j = 0; j < 8; ++j)
    att[b * T_ + tid + j * 256] = e[j] * inv;
}

// ---------------------------------------------------------------------------
// Pooling on bf16 t: pp[tc][b][d] = sum att * tb
// ---------------------------------------------------------------------------
__global__ __launch_bounds__(256) void k_pool_bf(const unsigned short* __restrict__ tb,
                                                 const float* __restrict__ att,
                                                 float* __restrict__ pp) {
  const int b = blockIdx.x, tc = blockIdx.y, tid = threadIdx.x;
  const uint2* tp = (const uint2*)tb;
  float4 acc = make_float4(0.f, 0.f, 0.f, 0.f);
  const int tbase = tc * 128;
  for (int i = 0; i < 128; ++i) {
    const int ti = tbase + i;
    const float wv = att[b * T_ + ti];
    const uint2 v = tp[(size_t)(b * T_ + ti) * 256 + tid];
    acc.x += wv * bfu(v.x & 0xffffu);
    acc.y += wv * bfu(v.x >> 16);
    acc.z += wv * bfu(v.y & 0xffffu);
    acc.w += wv * bfu(v.y >> 16);
  }
  ((float4*)pp)[(size_t)tc * 8192 + b * 256 + tid] = acc;
}

// Fallback pooling on fp32 t.
__global__ __launch_bounds__(256) void k_pool_f32(const float* __restrict__ t,
                                                  const float* __restrict__ att,
                                                  float* __restrict__ pp) {
  const int b = blockIdx.x, tc = blockIdx.y, tid = threadIdx.x;
  const float4* tp = (const float4*)t;
  float4 acc = make_float4(0.f, 0.f, 0.f, 0.f);
  const int tbase = tc * 128;
  for (int i = 0; i < 128; ++i) {
    const int ti = tbase + i;
    const float w = att[b * T_ + ti];
    const float4 v = tp[(size_t)(b * T_ + ti) * 256 + tid];
    acc.x += w * v.x; acc.y += w * v.y; acc.z += w * v.z; acc.w += w * v.w;
  }
  ((float4*)pp)[(size_t)tc * 8192 + b * 256 + tid] = acc;
}

__global__ __launch_bounds__(256) void k_pool_reduce(const float* __restrict__ pp,
                                                     float* __restrict__ out) {
  const int idx = blockIdx.x * 256 + threadIdx.x;  // 0 .. 32767
  float s = 0.f;
#pragma unroll
  for (int tc = 0; tc < 16; ++tc) s += pp[tc * 32768 + idx];
  out[idx] = s;
}

// ---------------------------------------------------------------------------
extern "C" void kernel_launch(void* const* d_in, const int* in_sizes, int n_in,
                              void* d_out, int out_size, void* d_ws, size_t ws_size,
                              hipStream_t stream) {
  const float* t    = (const float*)d_in[0];
  const float* a    = (const float*)d_in[1];
  const float* b    = (const float*)d_in[2];
  const void*  mask = d_in[3];
  const float* wt   = (const float*)d_in[4];
  const float* wa   = (const float*)d_in[5];
  const float* wb   = (const float*)d_in[6];
  const float* wh   = (const float*)d_in[7];
  float* out = (float*)d_out;

  float* ws = (float*)d_ws;
  const size_t NEED_FAST = (size_t)(33554432 + 32768 + 65536 + 524288 + 524288 + 524288) * 4;
  const bool fast = ws_size >= NEED_FAST;

  if (fast) {
    unsigned short* tb = (unsigned short*)ws;          // 128 MB
    float* g     = ws + 33554432;
    float* att   = g + 32768;
    float* spart = att + 65536;                        // 524288 floats (2 MB)
    float* pp    = spart + 524288;                     // 524288 floats (2 MB)
    unsigned short* wtT = (unsigned short*)(pp + 524288);
    float* gpa = spart;                                // overlay, freed by k_gfin
    float* gpb = pp;

    k_prep_stream<<<3584, 256, 0, stream>>>(t, (uint2*)tb, wt, wtT,
                                            a, b, wa, wb, gpa, gpb);
    k_gfin<<<128, 256, 0, stream>>>(gpa, gpb, wh, g);
    k_score_fast<<<2048, 512, 0, stream>>>(tb, wtT, g, spart);
    k_softmax<<<32, 256, 0, stream>>>(spart, mask, att, 8);
    k_pool_bf<<<dim3(32, 16), 256, 0, stream>>>(tb, att, pp);
    k_pool_reduce<<<128, 256, 0, stream>>>(pp, out);
  } else {
    float* g     = ws;
    float* att   = ws + 32768;
    float* spart = ws + 98304;                         // 524288 floats
    float* pp    = ws + 622592;                        // 524288 floats
    unsigned short* wtT = (unsigned short*)(ws + 1146880);
    float* gpa = spart;
    float* gpb = pp;

    // no-stream variant: only g + transpose blocks
    k_prep_stream<<<1536, 256, 0, stream>>>(t, (uint2*)ws, wt, wtT,
                                            a, b, wa, wb, gpa, gpb);
    k_gfin<<<128, 256, 0, stream>>>(gpa, gpb, wh, g);
    k_score_rs<<<dim3(8, 512), 256, 0, stream>>>(t, wtT, g, spart);
    k_softmax<<<32, 256, 0, stream>>>(spart, mask, att, 8);
    k_pool_f32<<<dim3(32, 16), 256, 0, stream>>>(t, att, pp);
    k_pool_reduce<<<128, 256, 0, stream>>>(pp, out);
  }
}